// Round 1
// baseline (219.833 us; speedup 1.0000x reference)
//
#include <hip/hip_runtime.h>
#include <hip/hip_bf16.h>

#define BATCH 8192
#define IN_F  2048
#define OUT_F 2048
#define QB    7.0f
#define EPSV  1e-5f

typedef _Float16 f16x8 __attribute__((ext_vector_type(8)));
typedef _Float16 f16x4 __attribute__((ext_vector_type(4)));
typedef float    f32x4 __attribute__((ext_vector_type(4)));

#define AS1(p) ((__attribute__((address_space(1))) void*)(p))
#define AS3(p) ((__attribute__((address_space(3))) void*)(p))

__device__ __forceinline__ float waveReduceSum(float v) {
#pragma unroll
  for (int off = 32; off > 0; off >>= 1) v += __shfl_xor(v, off, 64);
  return v;
}
__device__ __forceinline__ float waveReduceMax(float v) {
#pragma unroll
  for (int off = 32; off > 0; off >>= 1) v = fmaxf(v, __shfl_xor(v, off, 64));
  return v;
}

// ---------------- Kernel 1: weight binarization + beta ----------------
// one block per output row o: w_bin[o,i] = sign(w[o,i] - mean_i(w[o,:])) as f16
// beta[o] = mean_i |w[o,i]|
__global__ __launch_bounds__(256) void wbin_kernel(const float* __restrict__ w,
                                                   _Float16* __restrict__ wb,
                                                   float* __restrict__ betaOut) {
  const int row = blockIdx.x;
  const int t = threadIdx.x;
  const float* wr = w + (size_t)row * IN_F;
  float4 v0 = ((const float4*)wr)[t];
  float4 v1 = ((const float4*)wr)[t + 256];
  float s  = v0.x + v0.y + v0.z + v0.w + v1.x + v1.y + v1.z + v1.w;
  float sa = fabsf(v0.x) + fabsf(v0.y) + fabsf(v0.z) + fabsf(v0.w)
           + fabsf(v1.x) + fabsf(v1.y) + fabsf(v1.z) + fabsf(v1.w);
  __shared__ float red[8];
  float wsum = waveReduceSum(s);
  float wsa  = waveReduceSum(sa);
  const int wave = t >> 6, lane = t & 63;
  if (lane == 0) { red[wave] = wsum; red[4 + wave] = wsa; }
  __syncthreads();
  const float mu   = (red[0] + red[1] + red[2] + red[3]) * (1.0f / IN_F);
  const float beta = (red[4] + red[5] + red[6] + red[7]) * (1.0f / IN_F);
  if (t == 0) betaOut[row] = beta;

  _Float16* wbr = wb + (size_t)row * IN_F;
  auto sgn = [&](float xv) -> _Float16 {
    float d = xv - mu;
    return (_Float16)((d > 0.0f) ? 1.0f : (d < 0.0f ? -1.0f : 0.0f));
  };
  f16x4 q0 = { sgn(v0.x), sgn(v0.y), sgn(v0.z), sgn(v0.w) };
  f16x4 q1 = { sgn(v1.x), sgn(v1.y), sgn(v1.z), sgn(v1.w) };
  ((f16x4*)wbr)[t]       = q0;
  ((f16x4*)wbr)[t + 256] = q1;
}

// ---------------- Kernel 2: layernorm + clip-quant to f16 ----------------
// one block per batch row b: xln = (x-mu)*rsqrt(var+eps); gama = max(max|xln|, eps)
// xq = clip(xln * 7/gama, -7+eps, 7-eps) stored f16; gamaOut[b] = gama
__global__ __launch_bounds__(256) void lnq_kernel(const float* __restrict__ x,
                                                  _Float16* __restrict__ xq,
                                                  float* __restrict__ gamaOut) {
  const int row = blockIdx.x;
  const int t = threadIdx.x;
  const float* xr = x + (size_t)row * IN_F;
  float4 v0 = ((const float4*)xr)[t];
  float4 v1 = ((const float4*)xr)[t + 256];
  float s  = v0.x + v0.y + v0.z + v0.w + v1.x + v1.y + v1.z + v1.w;
  float s2 = v0.x*v0.x + v0.y*v0.y + v0.z*v0.z + v0.w*v0.w
           + v1.x*v1.x + v1.y*v1.y + v1.z*v1.z + v1.w*v1.w;
  __shared__ float red[8];
  float wsum  = waveReduceSum(s);
  float wsum2 = waveReduceSum(s2);
  const int wave = t >> 6, lane = t & 63;
  if (lane == 0) { red[wave] = wsum; red[4 + wave] = wsum2; }
  __syncthreads();
  const float mu  = (red[0] + red[1] + red[2] + red[3]) * (1.0f / IN_F);
  const float ex2 = (red[4] + red[5] + red[6] + red[7]) * (1.0f / IN_F);
  const float rstd = rsqrtf(fmaxf(ex2 - mu * mu, 0.0f) + EPSV);

  float n[8];
  n[0] = (v0.x - mu) * rstd; n[1] = (v0.y - mu) * rstd;
  n[2] = (v0.z - mu) * rstd; n[3] = (v0.w - mu) * rstd;
  n[4] = (v1.x - mu) * rstd; n[5] = (v1.y - mu) * rstd;
  n[6] = (v1.z - mu) * rstd; n[7] = (v1.w - mu) * rstd;
  float amax = 0.0f;
#pragma unroll
  for (int j = 0; j < 8; ++j) amax = fmaxf(amax, fabsf(n[j]));

  __syncthreads();  // red[] reuse
  float wmax = waveReduceMax(amax);
  if (lane == 0) red[wave] = wmax;
  __syncthreads();
  const float g = fmaxf(fmaxf(fmaxf(red[0], red[1]), fmaxf(red[2], red[3])), EPSV);
  if (t == 0) gamaOut[row] = g;

  const float qs = QB / g;
  const float lo = -QB + EPSV, hi = QB - EPSV;
  auto qz = [&](float v) -> _Float16 {
    return (_Float16)fminf(fmaxf(v * qs, lo), hi);
  };
  _Float16* xqr = xq + (size_t)row * IN_F;
  f16x4 q0 = { qz(n[0]), qz(n[1]), qz(n[2]), qz(n[3]) };
  f16x4 q1 = { qz(n[4]), qz(n[5]), qz(n[6]), qz(n[7]) };
  ((f16x4*)xqr)[t]       = q0;
  ((f16x4*)xqr)[t + 256] = q1;
}

// ---------------- Kernel 3: GEMM  out[b,o] = (xq[b,:] . wbin[o,:]) * beta[o]*gama[b]/7 + bias[o]
// A = xq [M=8192, K=2048] row-major f16 ; B = wbin [N=2048, K=2048] row-major f16 (B^T gemm)
// 128x128 tile, BK=32, 256 threads = 4 waves in 2x2, each wave 64x64 via 4x4 of 16x16x32 MFMA.
__global__ __launch_bounds__(256) void gemm_kernel(const _Float16* __restrict__ A,
                                                   const _Float16* __restrict__ B,
                                                   const float* __restrict__ beta,
                                                   const float* __restrict__ gama,
                                                   const float* __restrict__ bias,
                                                   float* __restrict__ out) {
  __shared__ __align__(16) _Float16 As[128 * 32];
  __shared__ __align__(16) _Float16 Bs[128 * 32];

  const int t = threadIdx.x;
  const int wave = t >> 6, lane = t & 63;
  const int mBase = blockIdx.y * 128;
  const int nBase = blockIdx.x * 128;
  const int wm = (wave >> 1) * 64;   // wave's m offset in tile
  const int wn = (wave & 1) * 64;    // wave's n offset in tile

  f32x4 acc[4][4];
#pragma unroll
  for (int i = 0; i < 4; ++i)
#pragma unroll
    for (int j = 0; j < 4; ++j) {
      f32x4 z = {0.0f, 0.0f, 0.0f, 0.0f};
      acc[i][j] = z;
    }

  // ---- staging layout: wave w stages LDS bytes [w*1024, w*1024+1024) per chunk
  // lane l -> lds elem w*512 + l*8 -> row = w*16 + l/4, col = (l&3)*8
  const int lrow = lane >> 2;
  const int lcol = (lane & 3) * 8;
  const _Float16* aG0 = A + (size_t)(mBase +      wave * 16 + lrow) * IN_F + lcol;
  const _Float16* aG1 = A + (size_t)(mBase + 64 + wave * 16 + lrow) * IN_F + lcol;
  const _Float16* bG0 = B + (size_t)(nBase +      wave * 16 + lrow) * IN_F + lcol;
  const _Float16* bG1 = B + (size_t)(nBase + 64 + wave * 16 + lrow) * IN_F + lcol;
  _Float16* aL0 = As + wave * 512;          // wave-uniform LDS bases (HW adds lane*16B)
  _Float16* aL1 = As + 2048 + wave * 512;
  _Float16* bL0 = Bs + wave * 512;
  _Float16* bL1 = Bs + 2048 + wave * 512;

  // ---- fragment read addresses: A-operand m = lane&15, k = (lane>>4)*8 + j
  const int fr = lane & 15;
  const int fk = (lane >> 4) * 8;
  const _Float16* aF = As + (wm + fr) * 32 + fk;
  const _Float16* bF = Bs + (wn + fr) * 32 + fk;

  for (int k0 = 0; k0 < IN_F; k0 += 32) {
    __builtin_amdgcn_global_load_lds(AS1(aG0 + k0), AS3(aL0), 16, 0, 0);
    __builtin_amdgcn_global_load_lds(AS1(aG1 + k0), AS3(aL1), 16, 0, 0);
    __builtin_amdgcn_global_load_lds(AS1(bG0 + k0), AS3(bL0), 16, 0, 0);
    __builtin_amdgcn_global_load_lds(AS1(bG1 + k0), AS3(bL1), 16, 0, 0);
    __syncthreads();   // drains vmcnt -> LDS visible

    f16x8 af[4], bf[4];
#pragma unroll
    for (int mi = 0; mi < 4; ++mi) af[mi] = *(const f16x8*)(aF + mi * 16 * 32);
#pragma unroll
    for (int ni = 0; ni < 4; ++ni) bf[ni] = *(const f16x8*)(bF + ni * 16 * 32);
#pragma unroll
    for (int mi = 0; mi < 4; ++mi)
#pragma unroll
      for (int ni = 0; ni < 4; ++ni)
        acc[mi][ni] = __builtin_amdgcn_mfma_f32_16x16x32_f16(af[mi], bf[ni], acc[mi][ni], 0, 0, 0);

    __syncthreads();   // all waves done with LDS before next stage overwrites
  }

  // ---- epilogue: C/D layout col=lane&15, row=(lane>>4)*4+reg
  const int orow0 = mBase + wm + ((lane >> 4) << 2);
  const int ocol0 = nBase + wn + (lane & 15);
#pragma unroll
  for (int mi = 0; mi < 4; ++mi) {
    const int rbase = orow0 + mi * 16;
    const float g0 = gama[rbase + 0];
    const float g1 = gama[rbase + 1];
    const float g2 = gama[rbase + 2];
    const float g3 = gama[rbase + 3];
#pragma unroll
    for (int ni = 0; ni < 4; ++ni) {
      const int c = ocol0 + ni * 16;
      const float bsc = beta[c] * (1.0f / QB);
      const float bv = bias[c];
      float* op = out + (size_t)rbase * OUT_F + c;
      op[0 * OUT_F] = acc[mi][ni][0] * (bsc * g0) + bv;
      op[1 * OUT_F] = acc[mi][ni][1] * (bsc * g1) + bv;
      op[2 * OUT_F] = acc[mi][ni][2] * (bsc * g2) + bv;
      op[3 * OUT_F] = acc[mi][ni][3] * (bsc * g3) + bv;
    }
  }
}

extern "C" void kernel_launch(void* const* d_in, const int* in_sizes, int n_in,
                              void* d_out, int out_size, void* d_ws, size_t ws_size,
                              hipStream_t stream) {
  const float* x      = (const float*)d_in[0];
  const float* weight = (const float*)d_in[1];
  const float* bias   = (const float*)d_in[2];
  float* out = (float*)d_out;

  char* ws = (char*)d_ws;
  _Float16* wbin = (_Float16*)ws;                                          // 8 MB
  _Float16* xq   = (_Float16*)(ws + (size_t)OUT_F * IN_F * 2);             // 32 MB
  float* betaW   = (float*)(ws + (size_t)OUT_F * IN_F * 2 + (size_t)BATCH * IN_F * 2);
  float* gamaX   = betaW + OUT_F;

  wbin_kernel<<<OUT_F, 256, 0, stream>>>(weight, wbin, betaW);
  lnq_kernel<<<BATCH, 256, 0, stream>>>(x, xq, gamaX);
  gemm_kernel<<<dim3(OUT_F / 128, BATCH / 128), 256, 0, stream>>>(xq, wbin, betaW, gamaX, bias, out);
}

// Round 2
// 202.426 us; speedup vs baseline: 1.0860x; 1.0860x over previous
//
#include <hip/hip_runtime.h>
#include <hip/hip_bf16.h>

#define BATCH 8192
#define IN_F  2048
#define OUT_F 2048
#define QB    7.0f
#define EPSV  1e-5f

typedef _Float16 f16x8 __attribute__((ext_vector_type(8)));
typedef _Float16 f16x4 __attribute__((ext_vector_type(4)));
typedef float    f32x4 __attribute__((ext_vector_type(4)));

#define AS1(p) ((__attribute__((address_space(1))) void*)(p))
#define AS3(p) ((__attribute__((address_space(3))) void*)(p))

__device__ __forceinline__ float waveReduceSum(float v) {
#pragma unroll
  for (int off = 32; off > 0; off >>= 1) v += __shfl_xor(v, off, 64);
  return v;
}
__device__ __forceinline__ float waveReduceMax(float v) {
#pragma unroll
  for (int off = 32; off > 0; off >>= 1) v = fmaxf(v, __shfl_xor(v, off, 64));
  return v;
}

// ---------------- Kernel 1: weight binarization + beta ----------------
__global__ __launch_bounds__(256) void wbin_kernel(const float* __restrict__ w,
                                                   _Float16* __restrict__ wb,
                                                   float* __restrict__ betaOut) {
  const int row = blockIdx.x;
  const int t = threadIdx.x;
  const float* wr = w + (size_t)row * IN_F;
  float4 v0 = ((const float4*)wr)[t];
  float4 v1 = ((const float4*)wr)[t + 256];
  float s  = v0.x + v0.y + v0.z + v0.w + v1.x + v1.y + v1.z + v1.w;
  float sa = fabsf(v0.x) + fabsf(v0.y) + fabsf(v0.z) + fabsf(v0.w)
           + fabsf(v1.x) + fabsf(v1.y) + fabsf(v1.z) + fabsf(v1.w);
  __shared__ float red[8];
  float wsum = waveReduceSum(s);
  float wsa  = waveReduceSum(sa);
  const int wave = t >> 6, lane = t & 63;
  if (lane == 0) { red[wave] = wsum; red[4 + wave] = wsa; }
  __syncthreads();
  const float mu   = (red[0] + red[1] + red[2] + red[3]) * (1.0f / IN_F);
  const float beta = (red[4] + red[5] + red[6] + red[7]) * (1.0f / IN_F);
  if (t == 0) betaOut[row] = beta;

  _Float16* wbr = wb + (size_t)row * IN_F;
  auto sgn = [&](float xv) -> _Float16 {
    float d = xv - mu;
    return (_Float16)((d > 0.0f) ? 1.0f : (d < 0.0f ? -1.0f : 0.0f));
  };
  f16x4 q0 = { sgn(v0.x), sgn(v0.y), sgn(v0.z), sgn(v0.w) };
  f16x4 q1 = { sgn(v1.x), sgn(v1.y), sgn(v1.z), sgn(v1.w) };
  ((f16x4*)wbr)[t]       = q0;
  ((f16x4*)wbr)[t + 256] = q1;
}

// ---------------- Kernel 2: layernorm + clip-quant to f16 ----------------
__global__ __launch_bounds__(256) void lnq_kernel(const float* __restrict__ x,
                                                  _Float16* __restrict__ xq,
                                                  float* __restrict__ gamaOut) {
  const int row = blockIdx.x;
  const int t = threadIdx.x;
  const float* xr = x + (size_t)row * IN_F;
  float4 v0 = ((const float4*)xr)[t];
  float4 v1 = ((const float4*)xr)[t + 256];
  float s  = v0.x + v0.y + v0.z + v0.w + v1.x + v1.y + v1.z + v1.w;
  float s2 = v0.x*v0.x + v0.y*v0.y + v0.z*v0.z + v0.w*v0.w
           + v1.x*v1.x + v1.y*v1.y + v1.z*v1.z + v1.w*v1.w;
  __shared__ float red[8];
  float wsum  = waveReduceSum(s);
  float wsum2 = waveReduceSum(s2);
  const int wave = t >> 6, lane = t & 63;
  if (lane == 0) { red[wave] = wsum; red[4 + wave] = wsum2; }
  __syncthreads();
  const float mu  = (red[0] + red[1] + red[2] + red[3]) * (1.0f / IN_F);
  const float ex2 = (red[4] + red[5] + red[6] + red[7]) * (1.0f / IN_F);
  const float rstd = rsqrtf(fmaxf(ex2 - mu * mu, 0.0f) + EPSV);

  float n[8];
  n[0] = (v0.x - mu) * rstd; n[1] = (v0.y - mu) * rstd;
  n[2] = (v0.z - mu) * rstd; n[3] = (v0.w - mu) * rstd;
  n[4] = (v1.x - mu) * rstd; n[5] = (v1.y - mu) * rstd;
  n[6] = (v1.z - mu) * rstd; n[7] = (v1.w - mu) * rstd;
  float amax = 0.0f;
#pragma unroll
  for (int j = 0; j < 8; ++j) amax = fmaxf(amax, fabsf(n[j]));

  __syncthreads();
  float wmax = waveReduceMax(amax);
  if (lane == 0) red[wave] = wmax;
  __syncthreads();
  const float g = fmaxf(fmaxf(fmaxf(red[0], red[1]), fmaxf(red[2], red[3])), EPSV);
  if (t == 0) gamaOut[row] = g;

  const float qs = QB / g;
  const float lo = -QB + EPSV, hi = QB - EPSV;
  auto qz = [&](float v) -> _Float16 {
    return (_Float16)fminf(fmaxf(v * qs, lo), hi);
  };
  _Float16* xqr = xq + (size_t)row * IN_F;
  f16x4 q0 = { qz(n[0]), qz(n[1]), qz(n[2]), qz(n[3]) };
  f16x4 q1 = { qz(n[4]), qz(n[5]), qz(n[6]), qz(n[7]) };
  ((f16x4*)xqr)[t]       = q0;
  ((f16x4*)xqr)[t + 256] = q1;
}

// ---------------- Kernel 3: GEMM, BK=64, XOR-swizzled LDS ----------------
// out[b,o] = (xq[b,:] . wbin[o,:]) * beta[o]*gama[b]/7 + bias[o]
// A = xq [8192,2048] f16 row-major; B = wbin [2048,2048] f16 row-major (B^T gemm).
// 128x128 tile, BK=64 (32 K-iters, 32 MFMA/barrier). LDS rows of 64 elems
// (128 B); chunk = 16 B (8 elems), 8 chunks/row. Swizzle: LDS slot s of row r
// holds global chunk (s - r) & 7, so fragment read of k-chunk kh of row r
// hits slot (kh + r) & 7 -> start bank 4*((kh+fr)&7): all 8 bank-quads per
// quarter-wave, 2-way only (free per m136).
__global__ __launch_bounds__(256) void gemm_kernel(const _Float16* __restrict__ A,
                                                   const _Float16* __restrict__ B,
                                                   const float* __restrict__ beta,
                                                   const float* __restrict__ gama,
                                                   const float* __restrict__ bias,
                                                   float* __restrict__ out) {
  __shared__ __align__(16) _Float16 As[128 * 64];
  __shared__ __align__(16) _Float16 Bs[128 * 64];

  const int t = threadIdx.x;
  const int wave = t >> 6, lane = t & 63;
  const int mBase = blockIdx.y * 128;
  const int nBase = blockIdx.x * 128;
  const int wm = (wave >> 1) * 64;
  const int wn = (wave & 1) * 64;

  f32x4 acc[4][4];
#pragma unroll
  for (int i = 0; i < 4; ++i)
#pragma unroll
    for (int j = 0; j < 4; ++j) {
      f32x4 z = {0.0f, 0.0f, 0.0f, 0.0f};
      acc[i][j] = z;
    }

  // ---- staging: instruction j (0..3), wave w covers rows j*32+w*8 .. +8.
  // lane l -> row lr = l>>3 within group, slot ls = l&7; fetch global chunk
  // g = (ls - lr) & 7  (swizzle).
  const int lr = lane >> 3;
  const int ls = lane & 7;
  const int g  = (ls - lr) & 7;
  const _Float16* aG[4];
  const _Float16* bG[4];
  _Float16* aL[4];
  _Float16* bL[4];
#pragma unroll
  for (int j = 0; j < 4; ++j) {
    const int rowInTile = j * 32 + wave * 8 + lr;
    aG[j] = A + (size_t)(mBase + rowInTile) * IN_F + g * 8;
    bG[j] = B + (size_t)(nBase + rowInTile) * IN_F + g * 8;
    aL[j] = As + (j * 32 + wave * 8) * 64;   // wave-uniform; HW adds lane*16B
    bL[j] = Bs + (j * 32 + wave * 8) * 64;
  }

  // ---- fragment read: row = wm/wn + fr + mi*16, k-chunk kh = kk*4 + (lane>>4)
  // slot = (kh + fr) & 7 ; kk=1 slot = kk=0 slot ^ 4 (add-4 mod 8 == xor 4)
  const int fr = lane & 15;
  const int kq = lane >> 4;            // 0..3
  const int s0 = (kq + fr) & 7;        // kk = 0 slot
  const _Float16* aF = As + (wm + fr) * 64;
  const _Float16* bF = Bs + (wn + fr) * 64;
  const int off0 = s0 * 8;
  const int off1 = (s0 ^ 4) * 8;

  for (int k0 = 0; k0 < IN_F; k0 += 64) {
#pragma unroll
    for (int j = 0; j < 4; ++j) {
      __builtin_amdgcn_global_load_lds(AS1(aG[j] + k0), AS3(aL[j]), 16, 0, 0);
      __builtin_amdgcn_global_load_lds(AS1(bG[j] + k0), AS3(bL[j]), 16, 0, 0);
    }
    __syncthreads();

#pragma unroll
    for (int kk = 0; kk < 2; ++kk) {
      const int koff = kk ? off1 : off0;
      f16x8 af[4], bf[4];
#pragma unroll
      for (int mi = 0; mi < 4; ++mi) af[mi] = *(const f16x8*)(aF + mi * 16 * 64 + koff);
#pragma unroll
      for (int ni = 0; ni < 4; ++ni) bf[ni] = *(const f16x8*)(bF + ni * 16 * 64 + koff);
#pragma unroll
      for (int mi = 0; mi < 4; ++mi)
#pragma unroll
        for (int ni = 0; ni < 4; ++ni)
          acc[mi][ni] = __builtin_amdgcn_mfma_f32_16x16x32_f16(af[mi], bf[ni], acc[mi][ni], 0, 0, 0);
    }
    __syncthreads();
  }

  // ---- epilogue: C/D layout col = lane&15, row = (lane>>4)*4 + reg
  const int orow0 = mBase + wm + (kq << 2);
  const int ocol0 = nBase + wn + fr;
#pragma unroll
  for (int mi = 0; mi < 4; ++mi) {
    const int rbase = orow0 + mi * 16;
    const float g0 = gama[rbase + 0];
    const float g1 = gama[rbase + 1];
    const float g2 = gama[rbase + 2];
    const float g3 = gama[rbase + 3];
#pragma unroll
    for (int ni = 0; ni < 4; ++ni) {
      const int c = ocol0 + ni * 16;
      const float bsc = beta[c] * (1.0f / QB);
      const float bv = bias[c];
      float* op = out + (size_t)rbase * OUT_F + c;
      op[0 * OUT_F] = acc[mi][ni][0] * (bsc * g0) + bv;
      op[1 * OUT_F] = acc[mi][ni][1] * (bsc * g1) + bv;
      op[2 * OUT_F] = acc[mi][ni][2] * (bsc * g2) + bv;
      op[3 * OUT_F] = acc[mi][ni][3] * (bsc * g3) + bv;
    }
  }
}

extern "C" void kernel_launch(void* const* d_in, const int* in_sizes, int n_in,
                              void* d_out, int out_size, void* d_ws, size_t ws_size,
                              hipStream_t stream) {
  const float* x      = (const float*)d_in[0];
  const float* weight = (const float*)d_in[1];
  const float* bias   = (const float*)d_in[2];
  float* out = (float*)d_out;

  char* ws = (char*)d_ws;
  _Float16* wbin = (_Float16*)ws;                                          // 8 MB
  _Float16* xq   = (_Float16*)(ws + (size_t)OUT_F * IN_F * 2);             // 32 MB
  float* betaW   = (float*)(ws + (size_t)OUT_F * IN_F * 2 + (size_t)BATCH * IN_F * 2);
  float* gamaX   = betaW + OUT_F;

  wbin_kernel<<<OUT_F, 256, 0, stream>>>(weight, wbin, betaW);
  lnq_kernel<<<BATCH, 256, 0, stream>>>(x, xq, gamaX);
  gemm_kernel<<<dim3(OUT_F / 128, BATCH / 128), 256, 0, stream>>>(xq, wbin, betaW, gamaX, bias, out);
}

// Round 3
// 201.524 us; speedup vs baseline: 1.0908x; 1.0045x over previous
//
#include <hip/hip_runtime.h>
#include <hip/hip_bf16.h>

#define BATCH 8192
#define IN_F  2048
#define OUT_F 2048
#define QB    7.0f
#define EPSV  1e-5f

typedef _Float16 f16x8  __attribute__((ext_vector_type(8)));
typedef _Float16 f16x4  __attribute__((ext_vector_type(4)));
typedef float    f32x16 __attribute__((ext_vector_type(16)));

#define AS1(p) ((__attribute__((address_space(1))) void*)(p))
#define AS3(p) ((__attribute__((address_space(3))) void*)(p))

__device__ __forceinline__ float waveReduceSum(float v) {
#pragma unroll
  for (int off = 32; off > 0; off >>= 1) v += __shfl_xor(v, off, 64);
  return v;
}
__device__ __forceinline__ float waveReduceMax(float v) {
#pragma unroll
  for (int off = 32; off > 0; off >>= 1) v = fmaxf(v, __shfl_xor(v, off, 64));
  return v;
}

// ---------------- Fused preprocessing ----------------
// blocks [0, OUT_F): weight binarization row  -> wbin (f16 ±1/0), beta
// blocks [OUT_F, OUT_F+BATCH): layernorm+quant row -> xq (f16), gama
__global__ __launch_bounds__(256) void prep_kernel(const float* __restrict__ x,
                                                   const float* __restrict__ w,
                                                   _Float16* __restrict__ xq,
                                                   _Float16* __restrict__ wb,
                                                   float* __restrict__ gamaOut,
                                                   float* __restrict__ betaOut) {
  __shared__ float red[8];
  const int t = threadIdx.x;
  const int wave = t >> 6, lane = t & 63;

  if (blockIdx.x < OUT_F) {
    // ---- weight binarization ----
    const int row = blockIdx.x;
    const float* wr = w + (size_t)row * IN_F;
    float4 v0 = ((const float4*)wr)[t];
    float4 v1 = ((const float4*)wr)[t + 256];
    float s  = v0.x + v0.y + v0.z + v0.w + v1.x + v1.y + v1.z + v1.w;
    float sa = fabsf(v0.x) + fabsf(v0.y) + fabsf(v0.z) + fabsf(v0.w)
             + fabsf(v1.x) + fabsf(v1.y) + fabsf(v1.z) + fabsf(v1.w);
    float wsum = waveReduceSum(s);
    float wsa  = waveReduceSum(sa);
    if (lane == 0) { red[wave] = wsum; red[4 + wave] = wsa; }
    __syncthreads();
    const float mu   = (red[0] + red[1] + red[2] + red[3]) * (1.0f / IN_F);
    const float beta = (red[4] + red[5] + red[6] + red[7]) * (1.0f / IN_F);
    if (t == 0) betaOut[row] = beta;

    _Float16* wbr = wb + (size_t)row * IN_F;
    auto sgn = [&](float xv) -> _Float16 {
      float d = xv - mu;
      return (_Float16)((d > 0.0f) ? 1.0f : (d < 0.0f ? -1.0f : 0.0f));
    };
    f16x4 q0 = { sgn(v0.x), sgn(v0.y), sgn(v0.z), sgn(v0.w) };
    f16x4 q1 = { sgn(v1.x), sgn(v1.y), sgn(v1.z), sgn(v1.w) };
    ((f16x4*)wbr)[t]       = q0;
    ((f16x4*)wbr)[t + 256] = q1;
  } else {
    // ---- layernorm + clip-quant ----
    const int row = blockIdx.x - OUT_F;
    const float* xr = x + (size_t)row * IN_F;
    float4 v0 = ((const float4*)xr)[t];
    float4 v1 = ((const float4*)xr)[t + 256];
    float s  = v0.x + v0.y + v0.z + v0.w + v1.x + v1.y + v1.z + v1.w;
    float s2 = v0.x*v0.x + v0.y*v0.y + v0.z*v0.z + v0.w*v0.w
             + v1.x*v1.x + v1.y*v1.y + v1.z*v1.z + v1.w*v1.w;
    float wsum  = waveReduceSum(s);
    float wsum2 = waveReduceSum(s2);
    if (lane == 0) { red[wave] = wsum; red[4 + wave] = wsum2; }
    __syncthreads();
    const float mu  = (red[0] + red[1] + red[2] + red[3]) * (1.0f / IN_F);
    const float ex2 = (red[4] + red[5] + red[6] + red[7]) * (1.0f / IN_F);
    const float rstd = rsqrtf(fmaxf(ex2 - mu * mu, 0.0f) + EPSV);

    float n[8];
    n[0] = (v0.x - mu) * rstd; n[1] = (v0.y - mu) * rstd;
    n[2] = (v0.z - mu) * rstd; n[3] = (v0.w - mu) * rstd;
    n[4] = (v1.x - mu) * rstd; n[5] = (v1.y - mu) * rstd;
    n[6] = (v1.z - mu) * rstd; n[7] = (v1.w - mu) * rstd;
    float amax = 0.0f;
#pragma unroll
    for (int j = 0; j < 8; ++j) amax = fmaxf(amax, fabsf(n[j]));

    __syncthreads();
    float wmax = waveReduceMax(amax);
    if (lane == 0) red[wave] = wmax;
    __syncthreads();
    const float g = fmaxf(fmaxf(fmaxf(red[0], red[1]), fmaxf(red[2], red[3])), EPSV);
    if (t == 0) gamaOut[row] = g;

    const float qs = QB / g;
    const float lo = -QB + EPSV, hi = QB - EPSV;
    auto qz = [&](float v) -> _Float16 {
      return (_Float16)fminf(fmaxf(v * qs, lo), hi);
    };
    _Float16* xqr = xq + (size_t)row * IN_F;
    f16x4 q0 = { qz(n[0]), qz(n[1]), qz(n[2]), qz(n[3]) };
    f16x4 q1 = { qz(n[4]), qz(n[5]), qz(n[6]), qz(n[7]) };
    ((f16x4*)xqr)[t]       = q0;
    ((f16x4*)xqr)[t + 256] = q1;
  }
}

// ---------------- GEMM: 128x128 tile, BK=64, XOR-swizzle, 32x32x16 MFMA ----
// out[b,o] = (xq[b,:] . wbin[o,:]) * beta[o]*gama[b]/7 + bias[o]
// A = xq [8192,2048] f16 row-major; B = wbin [2048,2048] f16 row-major.
// 4 waves in 2x2; each wave 64x64 = 2x2 of 32x32 MFMA tiles.
// LDS rows of 64 f16 (8 chunks of 16 B); chunk swizzle: slot s of row r holds
// global chunk (s-r)&7  -> fragment read of chunk kh hits slot (kh+r)&7.
// All tile row offsets (16/32/64) are ==0 mod 8, so slot depends only on
// (kh + lane-row) -> conflict-free (measured 0 in r2).
__global__ __launch_bounds__(256) void gemm_kernel(const _Float16* __restrict__ A,
                                                   const _Float16* __restrict__ B,
                                                   const float* __restrict__ beta,
                                                   const float* __restrict__ gama,
                                                   const float* __restrict__ bias,
                                                   float* __restrict__ out) {
  __shared__ __align__(16) _Float16 As[128 * 64];
  __shared__ __align__(16) _Float16 Bs[128 * 64];

  const int t = threadIdx.x;
  const int wave = t >> 6, lane = t & 63;
  const int mBase = blockIdx.y * 128;
  const int nBase = blockIdx.x * 128;
  const int wm = (wave >> 1) * 64;
  const int wn = (wave & 1) * 64;

  f32x16 acc[2][2];
#pragma unroll
  for (int i = 0; i < 2; ++i)
#pragma unroll
    for (int j = 0; j < 2; ++j)
#pragma unroll
      for (int r = 0; r < 16; ++r) acc[i][j][r] = 0.0f;

  // ---- staging: instr j covers rows j*32 + wave*8 .. +8; lane l -> row lr,
  // slot ls; fetch global chunk (ls - lr) & 7.
  const int lr = lane >> 3;
  const int ls = lane & 7;
  const int gch = (ls - lr) & 7;
  const _Float16* aG[4];
  const _Float16* bG[4];
  _Float16* aL[4];
  _Float16* bL[4];
#pragma unroll
  for (int j = 0; j < 4; ++j) {
    const int rowInTile = j * 32 + wave * 8 + lr;
    aG[j] = A + (size_t)(mBase + rowInTile) * IN_F + gch * 8;
    bG[j] = B + (size_t)(nBase + rowInTile) * IN_F + gch * 8;
    aL[j] = As + (j * 32 + wave * 8) * 64;   // wave-uniform; HW adds lane*16B
    bL[j] = Bs + (j * 32 + wave * 8) * 64;
  }

  // ---- fragment addressing: A[m= lane&31][k = (lane>>5)*8 + j]
  // k-chunk kh = ks*2 + (lane>>5); slot = (kh + (lane&31)) & 7
  const int fr32 = lane & 31;
  const int l5 = lane >> 5;
  const _Float16* aF = As + (wm + fr32) * 64;
  const _Float16* bF = Bs + (wn + fr32) * 64;
  int koff[4];
#pragma unroll
  for (int ks = 0; ks < 4; ++ks) koff[ks] = (((ks * 2 + l5 + fr32) & 7) * 8);

  for (int k0 = 0; k0 < IN_F; k0 += 64) {
#pragma unroll
    for (int j = 0; j < 4; ++j) {
      __builtin_amdgcn_global_load_lds(AS1(aG[j] + k0), AS3(aL[j]), 16, 0, 0);
      __builtin_amdgcn_global_load_lds(AS1(bG[j] + k0), AS3(bL[j]), 16, 0, 0);
    }
    __syncthreads();

#pragma unroll
    for (int ks = 0; ks < 4; ++ks) {
      f16x8 a0 = *(const f16x8*)(aF + koff[ks]);
      f16x8 a1 = *(const f16x8*)(aF + 32 * 64 + koff[ks]);
      f16x8 b0 = *(const f16x8*)(bF + koff[ks]);
      f16x8 b1 = *(const f16x8*)(bF + 32 * 64 + koff[ks]);
      acc[0][0] = __builtin_amdgcn_mfma_f32_32x32x16_f16(a0, b0, acc[0][0], 0, 0, 0);
      acc[0][1] = __builtin_amdgcn_mfma_f32_32x32x16_f16(a0, b1, acc[0][1], 0, 0, 0);
      acc[1][0] = __builtin_amdgcn_mfma_f32_32x32x16_f16(a1, b0, acc[1][0], 0, 0, 0);
      acc[1][1] = __builtin_amdgcn_mfma_f32_32x32x16_f16(a1, b1, acc[1][1], 0, 0, 0);
    }
    __syncthreads();
  }

  // ---- epilogue: C/D layout col = lane&31, row = (reg&3) + 8*(reg>>2) + 4*(lane>>5)
  const int r00 = mBase + wm + 4 * l5;
  const int c00 = nBase + wn + fr32;
#pragma unroll
  for (int mi = 0; mi < 2; ++mi) {
#pragma unroll
    for (int ni = 0; ni < 2; ++ni) {
      const int rowb = r00 + mi * 32;
      const int col  = c00 + ni * 32;
      const float bsc = beta[col] * (1.0f / QB);
      const float bv  = bias[col];
#pragma unroll
      for (int rg = 0; rg < 4; ++rg) {
#pragma unroll
        for (int rb = 0; rb < 4; ++rb) {
          const int row = rowb + 8 * rg + rb;
          out[(size_t)row * OUT_F + col] =
              acc[mi][ni][rg * 4 + rb] * (bsc * gama[row]) + bv;
        }
      }
    }
  }
}

extern "C" void kernel_launch(void* const* d_in, const int* in_sizes, int n_in,
                              void* d_out, int out_size, void* d_ws, size_t ws_size,
                              hipStream_t stream) {
  const float* x      = (const float*)d_in[0];
  const float* weight = (const float*)d_in[1];
  const float* bias   = (const float*)d_in[2];
  float* out = (float*)d_out;

  char* ws = (char*)d_ws;
  _Float16* wbin = (_Float16*)ws;                                          // 8 MB
  _Float16* xq   = (_Float16*)(ws + (size_t)OUT_F * IN_F * 2);             // 32 MB
  float* betaW   = (float*)(ws + (size_t)OUT_F * IN_F * 2 + (size_t)BATCH * IN_F * 2);
  float* gamaX   = betaW + OUT_F;

  prep_kernel<<<OUT_F + BATCH, 256, 0, stream>>>(x, weight, xq, wbin, gamaX, betaW);
  gemm_kernel<<<dim3(OUT_F / 128, BATCH / 128), 256, 0, stream>>>(xq, wbin, betaW, gamaX, bias, out);
}

// Round 4
// 170.199 us; speedup vs baseline: 1.2916x; 1.1841x over previous
//
#include <hip/hip_runtime.h>
#include <hip/hip_bf16.h>

#define BATCH 8192
#define IN_F  2048
#define OUT_F 2048
#define QB    7.0f
#define EPSV  1e-5f
#define ASCALE 18.0f            // xq_i8 = round(xq * 18) in [-126,126]

typedef char  i8x4 __attribute__((ext_vector_type(4)));
typedef int   i32x4 __attribute__((ext_vector_type(4)));

#define AS1(p) ((__attribute__((address_space(1))) void*)(p))
#define AS3(p) ((__attribute__((address_space(3))) void*)(p))

__device__ __forceinline__ float waveReduceSum(float v) {
#pragma unroll
  for (int off = 32; off > 0; off >>= 1) v += __shfl_xor(v, off, 64);
  return v;
}
__device__ __forceinline__ float waveReduceMax(float v) {
#pragma unroll
  for (int off = 32; off > 0; off >>= 1) v = fmaxf(v, __shfl_xor(v, off, 64));
  return v;
}

// ---------------- Fused preprocessing ----------------
// blocks [0, OUT_F): weight row -> wbin i8 {-1,0,1} (exact), beta
// blocks [OUT_F, OUT_F+BATCH): LN+clip row -> xq i8 = round(clip*18), gama
__global__ __launch_bounds__(256) void prep_kernel(const float* __restrict__ x,
                                                   const float* __restrict__ w,
                                                   char* __restrict__ xq,
                                                   char* __restrict__ wb,
                                                   float* __restrict__ gamaOut,
                                                   float* __restrict__ betaOut) {
  __shared__ float red[8];
  const int t = threadIdx.x;
  const int wave = t >> 6, lane = t & 63;

  if (blockIdx.x < OUT_F) {
    const int row = blockIdx.x;
    const float* wr = w + (size_t)row * IN_F;
    float4 v0 = ((const float4*)wr)[t];
    float4 v1 = ((const float4*)wr)[t + 256];
    float s  = v0.x + v0.y + v0.z + v0.w + v1.x + v1.y + v1.z + v1.w;
    float sa = fabsf(v0.x) + fabsf(v0.y) + fabsf(v0.z) + fabsf(v0.w)
             + fabsf(v1.x) + fabsf(v1.y) + fabsf(v1.z) + fabsf(v1.w);
    float wsum = waveReduceSum(s);
    float wsa  = waveReduceSum(sa);
    if (lane == 0) { red[wave] = wsum; red[4 + wave] = wsa; }
    __syncthreads();
    const float mu   = (red[0] + red[1] + red[2] + red[3]) * (1.0f / IN_F);
    const float beta = (red[4] + red[5] + red[6] + red[7]) * (1.0f / IN_F);
    if (t == 0) betaOut[row] = beta;

    char* wbr = wb + (size_t)row * IN_F;
    auto sgn = [&](float xv) -> char {
      float d = xv - mu;
      return (char)((d > 0.0f) ? 1 : (d < 0.0f ? -1 : 0));
    };
    i8x4 q0 = { sgn(v0.x), sgn(v0.y), sgn(v0.z), sgn(v0.w) };
    i8x4 q1 = { sgn(v1.x), sgn(v1.y), sgn(v1.z), sgn(v1.w) };
    ((i8x4*)wbr)[t]       = q0;
    ((i8x4*)wbr)[t + 256] = q1;
  } else {
    const int row = blockIdx.x - OUT_F;
    const float* xr = x + (size_t)row * IN_F;
    float4 v0 = ((const float4*)xr)[t];
    float4 v1 = ((const float4*)xr)[t + 256];
    float s  = v0.x + v0.y + v0.z + v0.w + v1.x + v1.y + v1.z + v1.w;
    float s2 = v0.x*v0.x + v0.y*v0.y + v0.z*v0.z + v0.w*v0.w
             + v1.x*v1.x + v1.y*v1.y + v1.z*v1.z + v1.w*v1.w;
    float wsum  = waveReduceSum(s);
    float wsum2 = waveReduceSum(s2);
    if (lane == 0) { red[wave] = wsum; red[4 + wave] = wsum2; }
    __syncthreads();
    const float mu  = (red[0] + red[1] + red[2] + red[3]) * (1.0f / IN_F);
    const float ex2 = (red[4] + red[5] + red[6] + red[7]) * (1.0f / IN_F);
    const float rstd = rsqrtf(fmaxf(ex2 - mu * mu, 0.0f) + EPSV);

    float n[8];
    n[0] = (v0.x - mu) * rstd; n[1] = (v0.y - mu) * rstd;
    n[2] = (v0.z - mu) * rstd; n[3] = (v0.w - mu) * rstd;
    n[4] = (v1.x - mu) * rstd; n[5] = (v1.y - mu) * rstd;
    n[6] = (v1.z - mu) * rstd; n[7] = (v1.w - mu) * rstd;
    float amax = 0.0f;
#pragma unroll
    for (int j = 0; j < 8; ++j) amax = fmaxf(amax, fabsf(n[j]));

    __syncthreads();
    float wmax = waveReduceMax(amax);
    if (lane == 0) red[wave] = wmax;
    __syncthreads();
    const float g = fmaxf(fmaxf(fmaxf(red[0], red[1]), fmaxf(red[2], red[3])), EPSV);
    if (t == 0) gamaOut[row] = g;

    // xq_i8 = round( clip(xln*7/g, -(7-eps), 7-eps) * 18 )  (|.| <= 126)
    const float qs = (QB * ASCALE) / g;           // 126/g
    const float lo = (-QB + EPSV) * ASCALE, hi = (QB - EPSV) * ASCALE;
    auto qz = [&](float v) -> char {
      return (char)__float2int_rn(fminf(fmaxf(v * qs, lo), hi));
    };
    char* xqr = xq + (size_t)row * IN_F;
    i8x4 q0 = { qz(n[0]), qz(n[1]), qz(n[2]), qz(n[3]) };
    i8x4 q1 = { qz(n[4]), qz(n[5]), qz(n[6]), qz(n[7]) };
    ((i8x4*)xqr)[t]       = q0;
    ((i8x4*)xqr)[t + 256] = q1;
  }
}

// ---------------- GEMM: i8, 128x128 tile, BK=128 elems (128 B rows) ----------
// out[b,o] = i32dot(xq_i8[b,:], wbin[o,:]) * beta[o]*gama[b]/(7*18) + bias[o]
// Exact r2-proven LDS scheme: rows of 128 B = 8 chunks of 16 B; slot s of row
// r holds global chunk (s-r)&7; fragment read of chunk kh from row fr hits
// slot (kh+fr)&7 -> per 16-lane group each bank-quad 2x (measured 0 conflicts).
// 4 waves 2x2, wave = 64x64 via 4x4 of 16x16x64 i8 MFMA; 16 K-iters.
__global__ __launch_bounds__(256) void gemm_kernel(const char* __restrict__ A,
                                                   const char* __restrict__ B,
                                                   const float* __restrict__ beta,
                                                   const float* __restrict__ gama,
                                                   const float* __restrict__ bias,
                                                   float* __restrict__ out) {
  __shared__ __align__(16) char As[128 * 128];
  __shared__ __align__(16) char Bs[128 * 128];

  const int t = threadIdx.x;
  const int wave = t >> 6, lane = t & 63;
  const int mBase = blockIdx.y * 128;
  const int nBase = blockIdx.x * 128;
  const int wm = (wave >> 1) * 64;
  const int wn = (wave & 1) * 64;

  i32x4 acc[4][4];
#pragma unroll
  for (int i = 0; i < 4; ++i)
#pragma unroll
    for (int j = 0; j < 4; ++j) {
      i32x4 z = {0, 0, 0, 0};
      acc[i][j] = z;
    }

  // ---- staging: instr j covers rows j*32 + wave*8 + (lane>>3); slot = lane&7
  // fetch global chunk (slot - row)&7  (row base == 0 mod 8 -> (ls - lr)&7)
  const int lr = lane >> 3;
  const int ls = lane & 7;
  const int gch = (ls - lr) & 7;
  const char* aG[4];
  const char* bG[4];
  char* aL[4];
  char* bL[4];
#pragma unroll
  for (int j = 0; j < 4; ++j) {
    const int rowInTile = j * 32 + wave * 8 + lr;
    aG[j] = A + (size_t)(mBase + rowInTile) * IN_F + gch * 16;
    bG[j] = B + (size_t)(nBase + rowInTile) * IN_F + gch * 16;
    aL[j] = As + (j * 32 + wave * 8) * 128;   // wave-uniform; HW adds lane*16B
    bL[j] = Bs + (j * 32 + wave * 8) * 128;
  }

  // ---- fragment: A[m=lane&15][k = (lane>>4)*16 + j], j=0..15 (16B chunk)
  // k-chunk kh = ks*4 + kq ; slot = (kh + fr) & 7
  const int fr = lane & 15;
  const int kq = lane >> 4;            // 0..3
  const char* aF = As + (wm + fr) * 128;
  const char* bF = Bs + (wn + fr) * 128;
  int koff[2];
#pragma unroll
  for (int ks = 0; ks < 2; ++ks) koff[ks] = ((ks * 4 + kq + fr) & 7) * 16;

  for (int k0 = 0; k0 < IN_F; k0 += 128) {
#pragma unroll
    for (int j = 0; j < 4; ++j) {
      __builtin_amdgcn_global_load_lds(AS1(aG[j] + k0), AS3(aL[j]), 16, 0, 0);
      __builtin_amdgcn_global_load_lds(AS1(bG[j] + k0), AS3(bL[j]), 16, 0, 0);
    }
    __syncthreads();

#pragma unroll
    for (int ks = 0; ks < 2; ++ks) {
      i32x4 af[4], bf[4];
#pragma unroll
      for (int mi = 0; mi < 4; ++mi) af[mi] = *(const i32x4*)(aF + mi * 16 * 128 + koff[ks]);
#pragma unroll
      for (int ni = 0; ni < 4; ++ni) bf[ni] = *(const i32x4*)(bF + ni * 16 * 128 + koff[ks]);
#pragma unroll
      for (int mi = 0; mi < 4; ++mi)
#pragma unroll
        for (int ni = 0; ni < 4; ++ni)
          acc[mi][ni] = __builtin_amdgcn_mfma_i32_16x16x64_i8(af[mi], bf[ni], acc[mi][ni], 0, 0, 0);
    }
    __syncthreads();
  }

  // ---- epilogue: C/D layout col = lane&15, row = (lane>>4)*4 + reg
  const float qinv = 1.0f / (QB * ASCALE);
  const int orow0 = mBase + wm + (kq << 2);
  const int ocol0 = nBase + wn + fr;
#pragma unroll
  for (int mi = 0; mi < 4; ++mi) {
    const int rbase = orow0 + mi * 16;
    const float g0 = gama[rbase + 0] * qinv;
    const float g1 = gama[rbase + 1] * qinv;
    const float g2 = gama[rbase + 2] * qinv;
    const float g3 = gama[rbase + 3] * qinv;
#pragma unroll
    for (int ni = 0; ni < 4; ++ni) {
      const int c = ocol0 + ni * 16;
      const float bsc = beta[c];
      const float bv  = bias[c];
      float* op = out + (size_t)rbase * OUT_F + c;
      op[0 * OUT_F] = (float)acc[mi][ni][0] * (bsc * g0) + bv;
      op[1 * OUT_F] = (float)acc[mi][ni][1] * (bsc * g1) + bv;
      op[2 * OUT_F] = (float)acc[mi][ni][2] * (bsc * g2) + bv;
      op[3 * OUT_F] = (float)acc[mi][ni][3] * (bsc * g3) + bv;
    }
  }
}

extern "C" void kernel_launch(void* const* d_in, const int* in_sizes, int n_in,
                              void* d_out, int out_size, void* d_ws, size_t ws_size,
                              hipStream_t stream) {
  const float* x      = (const float*)d_in[0];
  const float* weight = (const float*)d_in[1];
  const float* bias   = (const float*)d_in[2];
  float* out = (float*)d_out;

  char* ws = (char*)d_ws;
  char* wbin = ws;                                                  // 4 MB
  char* xq   = ws + (size_t)OUT_F * IN_F;                           // 16 MB
  float* betaW = (float*)(ws + (size_t)OUT_F * IN_F + (size_t)BATCH * IN_F);
  float* gamaX = betaW + OUT_F;

  prep_kernel<<<OUT_F + BATCH, 256, 0, stream>>>(x, weight, xq, wbin, gamaX, betaW);
  gemm_kernel<<<dim3(OUT_F / 128, BATCH / 128), 256, 0, stream>>>(xq, wbin, betaW, gamaX, bias, out);
}